// Round 1
// baseline (177.330 us; speedup 1.0000x reference)
//
#include <hip/hip_runtime.h>

#define BN_EPS 1e-5f

typedef _Float16 half8 __attribute__((ext_vector_type(8)));
typedef float f32x4 __attribute__((ext_vector_type(4)));

__device__ __forceinline__ float tanh_fast(float x){
  float e = __expf(2.0f * x);
  return 1.0f - 2.0f / (e + 1.0f);
}

// ---------------- prep: W1 -> fp16 copy (same row-major layout), BN scale/shift ----------------
__global__ __launch_bounds__(256) void k_prep(const float* __restrict__ W1,
    const float* __restrict__ gamma, const float* __restrict__ beta,
    const float* __restrict__ rmean, const float* __restrict__ rvar,
    _Float16* __restrict__ Bp, float* __restrict__ bns, float* __restrict__ bnb){
  int i = blockIdx.x * 256 + threadIdx.x;   // grid=256 -> covers 65536 = 256*256
  Bp[i] = (_Float16)W1[i];
  if (i < 4096){
    float sc = gamma[i] * rsqrtf(rvar[i] + BN_EPS);
    bns[i] = sc;
    bnb[i] = beta[i] - rmean[i] * sc;
  }
}

// ---------------- fused: a_t[b,s] = sum_e tanh(BN(sum_d x_hpre[b,s,d]*W1[e,d])) * x_h[b,e] ----------------
// workgroup: 256 thr (4 waves), one b, 64 s-rows. wave w owns e-cols [64w, 64w+64).
// MFMA 16x16x32 f16: A = x_hpre rows (M=64 x K=256), B[d,e] = W1[e,d] (K x N=256).
__global__ __launch_bounds__(256) void k_at(const float* __restrict__ xh,
    const float* __restrict__ xhpre, const _Float16* __restrict__ Bp,
    const float* __restrict__ bns, const float* __restrict__ bnb,
    float* __restrict__ a_t){
  constexpr int S = 4096, Dd = 256;
  const int bid = blockIdx.x;
  const int b  = bid >> 6;
  const int s0 = (bid & 63) * 64;
  const int tid = threadIdx.x;
  const int lane = tid & 63;
  const int w = tid >> 6;
  const int kg = lane >> 4;      // k-group 0..3 (8 k-elems each)
  const int lr = lane & 15;

  __shared__ _Float16 Alds[64][40];    // 40-halved stride (80B) breaks bank conflicts
  __shared__ _Float16 Blds[256][40];
  __shared__ float bnsc[64], bnsh[64];
  __shared__ float red[4][64];

  if (tid < 64){ bnsc[tid] = bns[s0 + tid]; bnsh[tid] = bnb[s0 + tid]; }

  const int wbase = w * 64;
  float xhv[4];
  #pragma unroll
  for (int nt = 0; nt < 4; ++nt) xhv[nt] = xh[b * 256 + wbase + nt * 16 + lr];

  f32x4 acc[4][4] = {};
  const float* Abase = xhpre + ((size_t)b * S + s0) * Dd;

  for (int k0 = 0; k0 < 256; k0 += 32){
    __syncthreads();
    // stage A: 64 rows x 32 k of x_hpre, f32 -> f16. 512 float4 loads, 2 per thread.
    #pragma unroll
    for (int p = 0; p < 2; ++p){
      int f = tid + p * 256;
      int row = f >> 3;
      int kk = (f & 7) << 2;
      float4 v4 = *reinterpret_cast<const float4*>(Abase + (size_t)row * Dd + k0 + kk);
      union { _Float16 h[4]; uint2 u; } pk;
      pk.h[0] = (_Float16)v4.x; pk.h[1] = (_Float16)v4.y;
      pk.h[2] = (_Float16)v4.z; pk.h[3] = (_Float16)v4.w;
      *reinterpret_cast<uint2*>(&Alds[row][kk]) = pk.u;
    }
    // stage B: thread e=tid copies 32 fp16 (64B) from Bp[e][k0..k0+31]
    {
      const uint4* bsrc = reinterpret_cast<const uint4*>(Bp + (size_t)tid * 256 + k0);
      #pragma unroll
      for (int j = 0; j < 4; ++j)
        *reinterpret_cast<uint4*>(&Blds[tid][j * 8]) = bsrc[j];
    }
    __syncthreads();

    half8 afr[4], bfr[4];
    #pragma unroll
    for (int mt = 0; mt < 4; ++mt)
      afr[mt] = *reinterpret_cast<const half8*>(&Alds[mt * 16 + lr][kg * 8]);
    #pragma unroll
    for (int nt = 0; nt < 4; ++nt)
      bfr[nt] = *reinterpret_cast<const half8*>(&Blds[wbase + nt * 16 + lr][kg * 8]);
    #pragma unroll
    for (int mt = 0; mt < 4; ++mt)
      #pragma unroll
      for (int nt = 0; nt < 4; ++nt)
        acc[mt][nt] = __builtin_amdgcn_mfma_f32_16x16x32_f16(afr[mt], bfr[nt], acc[mt][nt], 0, 0, 0);
  }

  // epilogue: BN + tanh + dot with x_h, reduce 64 cols per wave, then 4 waves via LDS
  #pragma unroll
  for (int mt = 0; mt < 4; ++mt){
    #pragma unroll
    for (int r = 0; r < 4; ++r){
      int row = mt * 16 + kg * 4 + r;   // C/D layout: col=lane&15, row=(lane>>4)*4+reg
      float sc = bnsc[row], sh = bnsh[row];
      float sum = 0.f;
      #pragma unroll
      for (int nt = 0; nt < 4; ++nt){
        float hv = fmaf(acc[mt][nt][r], sc, sh);
        sum = fmaf(tanh_fast(hv), xhv[nt], sum);
      }
      sum += __shfl_xor(sum, 1);
      sum += __shfl_xor(sum, 2);
      sum += __shfl_xor(sum, 4);
      sum += __shfl_xor(sum, 8);
      if (lr == 0) red[w][row] = sum;
    }
  }
  __syncthreads();
  if (tid < 64){
    float v = red[0][tid] + red[1][tid] + red[2][tid] + red[3][tid];
    a_t[(size_t)b * S + s0 + tid] = v;
  }
}

// ---------------- softmax over s (4096) per b ----------------
__global__ __launch_bounds__(256) void k_softmax(const float* __restrict__ at, float* __restrict__ as_){
  int b = blockIdx.x, tid = threadIdx.x;
  int w = tid >> 6, lane = tid & 63;
  __shared__ float rm[4], rz[4];
  float v[16];
  float m = -1e30f;
  #pragma unroll
  for (int i = 0; i < 16; ++i){ v[i] = at[(size_t)b * 4096 + i * 256 + tid]; m = fmaxf(m, v[i]); }
  #pragma unroll
  for (int o = 1; o < 64; o <<= 1) m = fmaxf(m, __shfl_xor(m, o));
  if (lane == 0) rm[w] = m;
  __syncthreads();
  m = fmaxf(fmaxf(rm[0], rm[1]), fmaxf(rm[2], rm[3]));
  float e[16], z = 0.f;
  #pragma unroll
  for (int i = 0; i < 16; ++i){ e[i] = __expf(v[i] - m); z += e[i]; }
  #pragma unroll
  for (int o = 1; o < 64; o <<= 1) z += __shfl_xor(z, o);
  if (lane == 0) rz[w] = z;
  __syncthreads();
  z = rz[0] + rz[1] + rz[2] + rz[3];
  float inv = 1.0f / z;
  #pragma unroll
  for (int i = 0; i < 16; ++i) as_[(size_t)b * 4096 + i * 256 + tid] = e[i] * inv;
}

// ---------------- partial weighted sums: partial[b,c,d] = sum_{s in chunk c} a_s * x_hpre ----------------
__global__ __launch_bounds__(256) void k_wsum(const float* __restrict__ as_,
    const float* __restrict__ xp, float* __restrict__ partial){
  int bid = blockIdx.x;
  int b = bid >> 4, c = bid & 15;
  int d = threadIdx.x;
  __shared__ float a[256];
  a[d] = as_[(size_t)b * 4096 + c * 256 + d];
  __syncthreads();
  const float* x = xp + ((size_t)(b * 4096 + c * 256)) * 256 + d;
  float acc = 0.f;
  #pragma unroll 8
  for (int s = 0; s < 256; ++s) acc = fmaf(a[s], x[(size_t)s * 256], acc);
  partial[(size_t)bid * 256 + d] = acc;
}

// ---------------- final: out[b,d] = W2[d] * sum_c partial ----------------
__global__ __launch_bounds__(256) void k_out(const float* __restrict__ partial,
    const float* __restrict__ W2, float* __restrict__ out){
  int b = blockIdx.x, d = threadIdx.x;
  float s = 0.f;
  #pragma unroll
  for (int c = 0; c < 16; ++c) s += partial[(size_t)(b * 16 + c) * 256 + d];
  out[b * 256 + d] = s * W2[d];
}

extern "C" void kernel_launch(void* const* d_in, const int* in_sizes, int n_in,
                              void* d_out, int out_size, void* d_ws, size_t ws_size,
                              hipStream_t stream){
  const float* x_h    = (const float*)d_in[0];
  const float* x_hpre = (const float*)d_in[1];
  const float* W1     = (const float*)d_in[2];
  const float* W2     = (const float*)d_in[3];
  const float* gamma  = (const float*)d_in[4];
  const float* beta   = (const float*)d_in[5];
  const float* rmean  = (const float*)d_in[6];
  const float* rvar   = (const float*)d_in[7];
  float* out = (float*)d_out;

  char* ws = (char*)d_ws;
  _Float16* Bp = (_Float16*)(ws);           // 131072 B
  float* bns  = (float*)(ws + 131072);      // 16 KB
  float* bnb  = (float*)(ws + 147456);      // 16 KB
  float* at   = (float*)(ws + 163840);      // 1 MB
  float* as_  = (float*)(ws + 1212416);     // 1 MB
  float* part = (float*)(ws + 2260992);     // 1 MB   (total ~3.2 MB)

  hipLaunchKernelGGL(k_prep,    dim3(256),  dim3(256), 0, stream, W1, gamma, beta, rmean, rvar, Bp, bns, bnb);
  hipLaunchKernelGGL(k_at,      dim3(4096), dim3(256), 0, stream, x_h, x_hpre, Bp, bns, bnb, at);
  hipLaunchKernelGGL(k_softmax, dim3(64),   dim3(256), 0, stream, at, as_);
  hipLaunchKernelGGL(k_wsum,    dim3(1024), dim3(256), 0, stream, as_, x_hpre, part);
  hipLaunchKernelGGL(k_out,     dim3(64),   dim3(256), 0, stream, part, W2, out);
}